// Round 1
// baseline (3142.345 us; speedup 1.0000x reference)
//
#include <hip/hip_runtime.h>

#define D 128

// ---------------- degree / normalization ----------------

__global__ void k_deg_init(float* deg, int n) {
    int i = blockIdx.x * blockDim.x + threadIdx.x;
    if (i < n) deg[i] = 1.0f;  // self-loop
}

__global__ void k_deg_count(const int* __restrict__ dst, float* deg, int e) {
    int i = blockIdx.x * blockDim.x + threadIdx.x;
    if (i < e) atomicAdd(&deg[dst[i]], 1.0f);
}

__global__ void k_dis(float* deg, int n) {
    int i = blockIdx.x * blockDim.x + threadIdx.x;
    if (i < n) deg[i] = rsqrtf(deg[i]);  // deg >= 1 always (self-loop)
}

// ---------------- GEMM: Y[r][c] = dis[r] * sum_k X[r][k]*W[k][c] ----------------
// Block: 256 threads, 64 rows per block, full 128x128 W staged in LDS (64KB).
// 4 row-groups of 64 threads; each thread computes cols (tc, tc+64) for its row.

__global__ __launch_bounds__(256) void k_gemm_scale(
    const float* __restrict__ X, const float* __restrict__ W,
    const float* __restrict__ dis, float* __restrict__ Y, int nrows) {
    __shared__ float sW[D * D];
    __shared__ float sX[4][D];
    {
        const float4* W4 = (const float4*)W;
        float4* sW4 = (float4*)sW;
        for (int i = threadIdx.x; i < D * D / 4; i += 256) sW4[i] = W4[i];
    }
    int row0 = blockIdx.x * 64;
    int tc = threadIdx.x & 63;
    int rsub = threadIdx.x >> 6;
    for (int r4 = 0; r4 < 64; r4 += 4) {
        __syncthreads();  // guards sW on first iter, sX reuse on later iters
        for (int i = threadIdx.x; i < 4 * D; i += 256) {
            int rr = i >> 7, cc = i & 127;
            int gr = row0 + r4 + rr;
            sX[rr][cc] = (gr < nrows) ? X[(size_t)gr * D + cc] : 0.0f;
        }
        __syncthreads();
        float acc0 = 0.f, acc1 = 0.f;
        #pragma unroll
        for (int k = 0; k < D; ++k) {
            float xv = sX[rsub][k];              // broadcast within wave
            acc0 += xv * sW[k * D + tc];         // lanes 0..63 consecutive -> conflict-free
            acc1 += xv * sW[k * D + tc + 64];
        }
        int gr = row0 + r4 + rsub;
        if (gr < nrows) {
            float dv = dis[gr];
            Y[(size_t)gr * D + tc] = acc0 * dv;
            Y[(size_t)gr * D + tc + 64] = acc1 * dv;
        }
    }
}

// ---------------- elementwise helpers ----------------

__global__ void k_copy4(const float4* __restrict__ in, float4* __restrict__ out, long n4) {
    long i = (long)blockIdx.x * blockDim.x + threadIdx.x;
    long stride = (long)gridDim.x * blockDim.x;
    for (; i < n4; i += stride) out[i] = in[i];
}

// 32 threads per edge, float4 each: gather g[src] row, atomic-add into agg[dst] row.
__global__ void k_scatter(const float* __restrict__ g, const int* __restrict__ ei,
                          float* __restrict__ agg, int ne) {
    long tid = (long)blockIdx.x * blockDim.x + threadIdx.x;
    int lane = (int)(tid & 31);
    long e = tid >> 5;
    if (e >= ne) return;
    int src = ei[e];
    int dst = ei[(long)ne + e];
    float4 v = ((const float4*)(g + (size_t)src * D))[lane];
    float* p = agg + (size_t)dst * D + lane * 4;
    atomicAdd(p + 0, v.x);
    atomicAdd(p + 1, v.y);
    atomicAdd(p + 2, v.z);
    atomicAdd(p + 3, v.w);
}

template <bool RELU>
__global__ void k_finish(float* __restrict__ buf, const float* __restrict__ dis,
                         const float* __restrict__ b, long n4) {
    long i = (long)blockIdx.x * blockDim.x + threadIdx.x;
    long stride = (long)gridDim.x * blockDim.x;
    const float4* b4 = (const float4*)b;
    for (; i < n4; i += stride) {
        long elem = i * 4;
        int node = (int)(elem >> 7);
        int c4 = (int)((elem & 127) >> 2);
        float dv = dis[node];
        float4 v = ((float4*)buf)[i];
        float4 bb = b4[c4];
        v.x = v.x * dv + bb.x;
        v.y = v.y * dv + bb.y;
        v.z = v.z * dv + bb.z;
        v.w = v.w * dv + bb.w;
        if (RELU) {
            v.x = fmaxf(v.x, 0.f);
            v.y = fmaxf(v.y, 0.f);
            v.z = fmaxf(v.z, 0.f);
            v.w = fmaxf(v.w, 0.f);
        }
        ((float4*)buf)[i] = v;
    }
}

// ---------------- launch ----------------

extern "C" void kernel_launch(void* const* d_in, const int* in_sizes, int n_in,
                              void* d_out, int out_size, void* d_ws, size_t ws_size,
                              hipStream_t stream) {
    const float* x  = (const float*)d_in[0];
    const int*   ei = (const int*)d_in[1];
    const float* W1 = (const float*)d_in[2];
    const float* b1 = (const float*)d_in[3];
    const float* W2 = (const float*)d_in[4];
    const float* b2 = (const float*)d_in[5];
    float* out = (float*)d_out;
    int n = in_sizes[0] / D;
    int e = in_sizes[1] / 2;

    char* ws = (char*)d_ws;
    float* dis = (float*)ws;
    size_t off = (((size_t)n * 4) + 255) & ~(size_t)255;
    size_t fbytes = (size_t)n * D * sizeof(float);
    float* bufA = (float*)(ws + off);
    float* bufB = (float*)(ws + off + fbytes);

    // normalization
    k_deg_init<<<(n + 255) / 256, 256, 0, stream>>>(dis, n);
    k_deg_count<<<(e + 255) / 256, 256, 0, stream>>>(ei + e, dis, e);
    k_dis<<<(n + 255) / 256, 256, 0, stream>>>(dis, n);

    int gemm_blocks = (n + 63) / 64;
    long n4 = (long)n * D / 4;
    int ew_blocks = (int)((n4 + 255) / 256);
    int scat_blocks = (int)(((long)e * 32 + 255) / 256);

    // layer 1: bufA = dis*(x@W1); bufB = agg; bufB = relu(dis*bufB + b1)
    k_gemm_scale<<<gemm_blocks, 256, 0, stream>>>(x, W1, dis, bufA, n);
    k_copy4<<<ew_blocks, 256, 0, stream>>>((const float4*)bufA, (float4*)bufB, n4);
    k_scatter<<<scat_blocks, 256, 0, stream>>>(bufA, ei, bufB, e);
    k_finish<true><<<ew_blocks, 256, 0, stream>>>(bufB, dis, b1, n4);

    // layer 2: bufA = dis*(bufB@W2); out = agg; out = dis*out + b2
    k_gemm_scale<<<gemm_blocks, 256, 0, stream>>>(bufB, W2, dis, bufA, n);
    k_copy4<<<ew_blocks, 256, 0, stream>>>((const float4*)bufA, (float4*)out, n4);
    k_scatter<<<scat_blocks, 256, 0, stream>>>(bufA, ei, out, e);
    k_finish<false><<<ew_blocks, 256, 0, stream>>>(out, dis, b2, n4);
}

// Round 3
// 604.011 us; speedup vs baseline: 5.2025x; 5.2025x over previous
//
#include <hip/hip_runtime.h>

#define D 128

// ================= CSR build (counting sort by dst) =================

__global__ void k_count(const int* __restrict__ dst, int* __restrict__ cnt, int e) {
    int i = blockIdx.x * blockDim.x + threadIdx.x;
    if (i < e) atomicAdd(&cnt[dst[i]], 1);
}

__global__ void k_dis(const int* __restrict__ cnt, float* __restrict__ dis, int n) {
    int i = blockIdx.x * blockDim.x + threadIdx.x;
    if (i < n) dis[i] = rsqrtf(1.0f + (float)cnt[i]);  // deg = 1 (self) + indegree
}

// exclusive scan, stage 1: per-block scan of 256 counts
__global__ __launch_bounds__(256) void k_scan1(const int* __restrict__ cnt,
                                               int* __restrict__ row_ptr,
                                               int* __restrict__ bsum, int n) {
    __shared__ int s[256];
    int i = blockIdx.x * 256 + threadIdx.x;
    int v = (i < n) ? cnt[i] : 0;
    s[threadIdx.x] = v;
    __syncthreads();
    for (int o = 1; o < 256; o <<= 1) {
        int t = (threadIdx.x >= o) ? s[threadIdx.x - o] : 0;
        __syncthreads();
        s[threadIdx.x] += t;
        __syncthreads();
    }
    if (i < n) row_ptr[i] = s[threadIdx.x] - v;  // exclusive
    if (threadIdx.x == 255) bsum[blockIdx.x] = s[255];
}

// stage 2: single-block exclusive scan of block sums (nb <= 256; n <= 65536)
__global__ __launch_bounds__(256) void k_scan2(int* __restrict__ bsum, int nb) {
    __shared__ int s[256];
    int v = (threadIdx.x < nb) ? bsum[threadIdx.x] : 0;
    s[threadIdx.x] = v;
    __syncthreads();
    for (int o = 1; o < 256; o <<= 1) {
        int t = (threadIdx.x >= o) ? s[threadIdx.x - o] : 0;
        __syncthreads();
        s[threadIdx.x] += t;
        __syncthreads();
    }
    if (threadIdx.x < nb) bsum[threadIdx.x] = s[threadIdx.x] - v;
}

// stage 3: add block offsets
__global__ void k_scan3(int* __restrict__ row_ptr, const int* __restrict__ bsum, int n) {
    int i = blockIdx.x * 256 + threadIdx.x;
    if (i < n) row_ptr[i] += bsum[blockIdx.x];
}

// place src ids into dst-sorted order
__global__ void k_place(const int* __restrict__ ei, const int* __restrict__ row_ptr,
                        int* __restrict__ fill, int* __restrict__ srcs, int e) {
    int i = blockIdx.x * blockDim.x + threadIdx.x;
    if (i < e) {
        int s_ = ei[i];
        int d_ = ei[e + i];
        int pos = row_ptr[d_] + atomicAdd(&fill[d_], 1);
        srcs[pos] = s_;
    }
}

// ================= GEMM: Y[r][c] = dis[r] * sum_k X[r][k]*W[k][c] =================
// 256 threads, 64 rows per block, full 128x128 W in LDS (64KB).

__global__ __launch_bounds__(256) void k_gemm_scale(
    const float* __restrict__ X, const float* __restrict__ W,
    const float* __restrict__ dis, float* __restrict__ Y, int nrows) {
    __shared__ float sW[D * D];
    __shared__ float sX[4][D];
    {
        const float4* W4 = (const float4*)W;
        float4* sW4 = (float4*)sW;
        for (int i = threadIdx.x; i < D * D / 4; i += 256) sW4[i] = W4[i];
    }
    int row0 = blockIdx.x * 64;
    int tc = threadIdx.x & 63;
    int rsub = threadIdx.x >> 6;
    for (int r4 = 0; r4 < 64; r4 += 4) {
        __syncthreads();
        for (int i = threadIdx.x; i < 4 * D; i += 256) {
            int rr = i >> 7, cc = i & 127;
            int gr = row0 + r4 + rr;
            sX[rr][cc] = (gr < nrows) ? X[(size_t)gr * D + cc] : 0.0f;
        }
        __syncthreads();
        float acc0 = 0.f, acc1 = 0.f;
        #pragma unroll
        for (int k = 0; k < D; ++k) {
            float xv = sX[rsub][k];
            acc0 += xv * sW[k * D + tc];
            acc1 += xv * sW[k * D + tc + 64];
        }
        int gr = row0 + r4 + rsub;
        if (gr < nrows) {
            float dv = dis[gr];
            Y[(size_t)gr * D + tc] = acc0 * dv;
            Y[(size_t)gr * D + tc + 64] = acc1 * dv;
        }
    }
}

// ================= fused aggregate + norm + bias (+relu) =================
// 32 lanes per node, float4 per lane. out[v] = act(dis[v]*(g[v] + sum g[src]) + b)

template <bool RELU>
__global__ __launch_bounds__(256) void k_aggregate(
    const float* __restrict__ g, const int* __restrict__ row_ptr,
    const int* __restrict__ cnt, const int* __restrict__ srcs,
    const float* __restrict__ dis, const float* __restrict__ b,
    float* __restrict__ out, int n) {
    long tid = (long)blockIdx.x * blockDim.x + threadIdx.x;
    int lane = (int)(tid & 31);
    int v = (int)(tid >> 5);
    if (v >= n) return;
    int beg = row_ptr[v];
    int c = cnt[v];
    const float4* g4 = (const float4*)g;
    float4 acc = g4[(size_t)v * 32 + lane];  // self-loop term
    for (int j = 0; j < c; ++j) {
        int u = srcs[beg + j];
        float4 t = g4[(size_t)u * 32 + lane];
        acc.x += t.x; acc.y += t.y; acc.z += t.z; acc.w += t.w;
    }
    float dv = dis[v];
    float4 bb = ((const float4*)b)[lane];
    acc.x = acc.x * dv + bb.x;
    acc.y = acc.y * dv + bb.y;
    acc.z = acc.z * dv + bb.z;
    acc.w = acc.w * dv + bb.w;
    if (RELU) {
        acc.x = fmaxf(acc.x, 0.f);
        acc.y = fmaxf(acc.y, 0.f);
        acc.z = fmaxf(acc.z, 0.f);
        acc.w = fmaxf(acc.w, 0.f);
    }
    ((float4*)out)[(size_t)v * 32 + lane] = acc;
}

// ================= launch =================

extern "C" void kernel_launch(void* const* d_in, const int* in_sizes, int n_in,
                              void* d_out, int out_size, void* d_ws, size_t ws_size,
                              hipStream_t stream) {
    const float* x  = (const float*)d_in[0];
    const int*   ei = (const int*)d_in[1];
    const float* W1 = (const float*)d_in[2];
    const float* b1 = (const float*)d_in[3];
    const float* W2 = (const float*)d_in[4];
    const float* b2 = (const float*)d_in[5];
    float* out = (float*)d_out;
    int n = in_sizes[0] / D;
    int e = in_sizes[1] / 2;

    char* p = (char*)d_ws;
    auto alloc = [&](size_t bytes) -> char* {
        char* r = p;
        p += (bytes + 255) & ~(size_t)255;
        return r;
    };
    int* cnt     = (int*)alloc((size_t)n * 4);
    int* fill    = (int*)alloc((size_t)n * 4);
    int* row_ptr = (int*)alloc((size_t)n * 4);
    int* bsum    = (int*)alloc(1024);
    float* dis   = (float*)alloc((size_t)n * 4);
    int* srcs    = (int*)alloc((size_t)e * 4);
    float* bufA  = (float*)alloc((size_t)n * D * 4);
    float* bufB  = (float*)alloc((size_t)n * D * 4);

    hipMemsetAsync(cnt, 0, (size_t)n * 4, stream);
    hipMemsetAsync(fill, 0, (size_t)n * 4, stream);

    int nb = (n + 255) / 256;
    k_count<<<(e + 255) / 256, 256, 0, stream>>>(ei + e, cnt, e);
    k_dis<<<nb, 256, 0, stream>>>(cnt, dis, n);
    k_scan1<<<nb, 256, 0, stream>>>(cnt, row_ptr, bsum, n);
    k_scan2<<<1, 256, 0, stream>>>(bsum, nb);
    k_scan3<<<nb, 256, 0, stream>>>(row_ptr, bsum, n);
    k_place<<<(e + 255) / 256, 256, 0, stream>>>(ei, row_ptr, fill, srcs, e);

    int gemm_blocks = (n + 63) / 64;
    int agg_blocks = (int)(((long)n * 32 + 255) / 256);

    // layer 1
    k_gemm_scale<<<gemm_blocks, 256, 0, stream>>>(x, W1, dis, bufA, n);
    k_aggregate<true><<<agg_blocks, 256, 0, stream>>>(bufA, row_ptr, cnt, srcs, dis, b1, bufB, n);
    // layer 2
    k_gemm_scale<<<gemm_blocks, 256, 0, stream>>>(bufB, W2, dis, bufA, n);
    k_aggregate<false><<<agg_blocks, 256, 0, stream>>>(bufA, row_ptr, cnt, srcs, dis, b2, out, n);
}

// Round 4
// 362.342 us; speedup vs baseline: 8.6723x; 1.6670x over previous
//
#include <hip/hip_runtime.h>

#define D 128
#define BM 128
#define BK 32

// ================= CSR build (counting sort by dst) =================

__global__ void k_count(const int* __restrict__ dst, int* __restrict__ cnt, int e) {
    int i = blockIdx.x * blockDim.x + threadIdx.x;
    if (i < e) atomicAdd(&cnt[dst[i]], 1);
}

__global__ void k_dis(const int* __restrict__ cnt, float* __restrict__ dis, int n) {
    int i = blockIdx.x * blockDim.x + threadIdx.x;
    if (i < n) dis[i] = rsqrtf(1.0f + (float)cnt[i]);  // deg = 1 (self) + indegree
}

__global__ __launch_bounds__(256) void k_scan1(const int* __restrict__ cnt,
                                               int* __restrict__ row_ptr,
                                               int* __restrict__ bsum, int n) {
    __shared__ int s[256];
    int i = blockIdx.x * 256 + threadIdx.x;
    int v = (i < n) ? cnt[i] : 0;
    s[threadIdx.x] = v;
    __syncthreads();
    for (int o = 1; o < 256; o <<= 1) {
        int t = (threadIdx.x >= o) ? s[threadIdx.x - o] : 0;
        __syncthreads();
        s[threadIdx.x] += t;
        __syncthreads();
    }
    if (i < n) row_ptr[i] = s[threadIdx.x] - v;  // exclusive
    if (threadIdx.x == 255) bsum[blockIdx.x] = s[255];
}

__global__ __launch_bounds__(256) void k_scan2(int* __restrict__ bsum, int nb) {
    __shared__ int s[256];
    int v = (threadIdx.x < nb) ? bsum[threadIdx.x] : 0;
    s[threadIdx.x] = v;
    __syncthreads();
    for (int o = 1; o < 256; o <<= 1) {
        int t = (threadIdx.x >= o) ? s[threadIdx.x - o] : 0;
        __syncthreads();
        s[threadIdx.x] += t;
        __syncthreads();
    }
    if (threadIdx.x < nb) bsum[threadIdx.x] = s[threadIdx.x] - v;
}

__global__ void k_scan3(int* __restrict__ row_ptr, const int* __restrict__ bsum, int n) {
    int i = blockIdx.x * 256 + threadIdx.x;
    if (i < n) row_ptr[i] += bsum[blockIdx.x];
}

__global__ void k_place(const int* __restrict__ ei, const int* __restrict__ row_ptr,
                        int* __restrict__ fill, int* __restrict__ srcs, int e) {
    int i = blockIdx.x * blockDim.x + threadIdx.x;
    if (i < e) {
        int s_ = ei[i];
        int d_ = ei[e + i];
        int pos = row_ptr[d_] + atomicAdd(&fill[d_], 1);
        srcs[pos] = s_;
    }
}

// ========= GEMM: Y[r][c] = dis[r] * sum_k X[r][k]*W[k][c] =========
// 128x128 block tile, BK=32 LDS-staged chunks, 256 threads, 8x8 register
// micro-tile per thread. Per k: 4x ds_read_b128 -> 64 FMA (FMA-issue-bound).
// LDS = 32*132*4 + 32*128*4 = 33.4 KB -> 4 blocks/CU.

__global__ __launch_bounds__(256) void k_gemm_scale(
    const float* __restrict__ X, const float* __restrict__ W,
    const float* __restrict__ dis, float* __restrict__ Y, int nrows) {
    __shared__ float sA[BK][BM + 4];  // transposed X chunk: sA[k][m]
    __shared__ float sB[BK][D];       // W chunk: sB[k][n]
    int tid = threadIdx.x;
    int tx = tid & 15;   // output cols tx*8 .. +7
    int ty = tid >> 4;   // output rows ty*8 .. +7
    int row0 = blockIdx.x * BM;

    float acc[8][8] = {};

    for (int kc = 0; kc < D; kc += BK) {
        __syncthreads();  // protect LDS from previous iteration's readers
        // stage A: X[row0..+127][kc..+31] transposed into sA[k][m]
        #pragma unroll
        for (int j = 0; j < 4; ++j) {
            int i = tid + j * 256;      // 0..1023 float4s
            int r = i >> 3;             // 0..127 row within tile
            int kq = i & 7;             // float4 index within 32-k window
            int gr = row0 + r;
            float4 v = make_float4(0.f, 0.f, 0.f, 0.f);
            if (gr < nrows) v = *(const float4*)(X + (size_t)gr * D + kc + kq * 4);
            sA[kq * 4 + 0][r] = v.x;
            sA[kq * 4 + 1][r] = v.y;
            sA[kq * 4 + 2][r] = v.z;
            sA[kq * 4 + 3][r] = v.w;
        }
        // stage B: W[kc..+31][0..127] into sB (direct, coalesced)
        #pragma unroll
        for (int j = 0; j < 4; ++j) {
            int i = tid + j * 256;      // 0..1023 float4s
            int k = i >> 5;             // 0..31
            int nq = i & 31;            // float4 col
            *(float4*)(&sB[k][nq * 4]) = *(const float4*)(W + (size_t)(kc + k) * D + nq * 4);
        }
        __syncthreads();
        #pragma unroll
        for (int k = 0; k < BK; ++k) {
            float a[8], b[8];
            *(float4*)&a[0] = *(float4*)&sA[k][ty * 8];
            *(float4*)&a[4] = *(float4*)&sA[k][ty * 8 + 4];
            *(float4*)&b[0] = *(float4*)&sB[k][tx * 8];
            *(float4*)&b[4] = *(float4*)&sB[k][tx * 8 + 4];
            #pragma unroll
            for (int i = 0; i < 8; ++i)
                #pragma unroll
                for (int j2 = 0; j2 < 8; ++j2)
                    acc[i][j2] += a[i] * b[j2];
        }
    }
    #pragma unroll
    for (int i = 0; i < 8; ++i) {
        int gr = row0 + ty * 8 + i;
        if (gr < nrows) {
            float dv = dis[gr];
            float4 o0, o1;
            o0.x = acc[i][0] * dv; o0.y = acc[i][1] * dv;
            o0.z = acc[i][2] * dv; o0.w = acc[i][3] * dv;
            o1.x = acc[i][4] * dv; o1.y = acc[i][5] * dv;
            o1.z = acc[i][6] * dv; o1.w = acc[i][7] * dv;
            *(float4*)(Y + (size_t)gr * D + tx * 8) = o0;
            *(float4*)(Y + (size_t)gr * D + tx * 8 + 4) = o1;
        }
    }
}

// ================= fused aggregate + norm + bias (+relu) =================
// 32 lanes per node, float4 per lane. out[v] = act(dis[v]*(g[v] + sum g[src]) + b)

template <bool RELU>
__global__ __launch_bounds__(256) void k_aggregate(
    const float* __restrict__ g, const int* __restrict__ row_ptr,
    const int* __restrict__ cnt, const int* __restrict__ srcs,
    const float* __restrict__ dis, const float* __restrict__ b,
    float* __restrict__ out, int n) {
    long tid = (long)blockIdx.x * blockDim.x + threadIdx.x;
    int lane = (int)(tid & 31);
    int v = (int)(tid >> 5);
    if (v >= n) return;
    int beg = row_ptr[v];
    int c = cnt[v];
    const float4* g4 = (const float4*)g;
    float4 acc = g4[(size_t)v * 32 + lane];  // self-loop term
    for (int j = 0; j < c; ++j) {
        int u = srcs[beg + j];
        float4 t = g4[(size_t)u * 32 + lane];
        acc.x += t.x; acc.y += t.y; acc.z += t.z; acc.w += t.w;
    }
    float dv = dis[v];
    float4 bb = ((const float4*)b)[lane];
    acc.x = acc.x * dv + bb.x;
    acc.y = acc.y * dv + bb.y;
    acc.z = acc.z * dv + bb.z;
    acc.w = acc.w * dv + bb.w;
    if (RELU) {
        acc.x = fmaxf(acc.x, 0.f);
        acc.y = fmaxf(acc.y, 0.f);
        acc.z = fmaxf(acc.z, 0.f);
        acc.w = fmaxf(acc.w, 0.f);
    }
    ((float4*)out)[(size_t)v * 32 + lane] = acc;
}

// ================= launch =================

extern "C" void kernel_launch(void* const* d_in, const int* in_sizes, int n_in,
                              void* d_out, int out_size, void* d_ws, size_t ws_size,
                              hipStream_t stream) {
    const float* x  = (const float*)d_in[0];
    const int*   ei = (const int*)d_in[1];
    const float* W1 = (const float*)d_in[2];
    const float* b1 = (const float*)d_in[3];
    const float* W2 = (const float*)d_in[4];
    const float* b2 = (const float*)d_in[5];
    float* out = (float*)d_out;
    int n = in_sizes[0] / D;
    int e = in_sizes[1] / 2;

    char* p = (char*)d_ws;
    auto alloc = [&](size_t bytes) -> char* {
        char* r = p;
        p += (bytes + 255) & ~(size_t)255;
        return r;
    };
    int* cnt     = (int*)alloc((size_t)n * 4);
    int* fill    = (int*)alloc((size_t)n * 4);
    int* row_ptr = (int*)alloc((size_t)n * 4);
    int* bsum    = (int*)alloc(1024);
    float* dis   = (float*)alloc((size_t)n * 4);
    int* srcs    = (int*)alloc((size_t)e * 4);
    float* bufA  = (float*)alloc((size_t)n * D * 4);
    float* bufB  = (float*)alloc((size_t)n * D * 4);

    hipMemsetAsync(cnt, 0, (size_t)n * 4, stream);
    hipMemsetAsync(fill, 0, (size_t)n * 4, stream);

    int nb = (n + 255) / 256;
    k_count<<<(e + 255) / 256, 256, 0, stream>>>(ei + e, cnt, e);
    k_dis<<<nb, 256, 0, stream>>>(cnt, dis, n);
    k_scan1<<<nb, 256, 0, stream>>>(cnt, row_ptr, bsum, n);
    k_scan2<<<1, 256, 0, stream>>>(bsum, nb);
    k_scan3<<<nb, 256, 0, stream>>>(row_ptr, bsum, n);
    k_place<<<(e + 255) / 256, 256, 0, stream>>>(ei, row_ptr, fill, srcs, e);

    int gemm_blocks = (n + BM - 1) / BM;
    int agg_blocks = (int)(((long)n * 32 + 255) / 256);

    // layer 1
    k_gemm_scale<<<gemm_blocks, 256, 0, stream>>>(x, W1, dis, bufA, n);
    k_aggregate<true><<<agg_blocks, 256, 0, stream>>>(bufA, row_ptr, cnt, srcs, dis, b1, bufB, n);
    // layer 2
    k_gemm_scale<<<gemm_blocks, 256, 0, stream>>>(bufB, W2, dis, bufA, n);
    k_aggregate<false><<<agg_blocks, 256, 0, stream>>>(bufA, row_ptr, cnt, srcs, dis, b2, out, n);
}

// Round 5
// 343.217 us; speedup vs baseline: 9.1556x; 1.0557x over previous
//
#include <hip/hip_runtime.h>

#define D 128
#define GBM 64
#define GBK 32

// ================= CSR build (counting sort by dst) =================

__global__ void k_count(const int* __restrict__ dst, int* __restrict__ cnt, int e) {
    int i = blockIdx.x * blockDim.x + threadIdx.x;
    if (i < e) atomicAdd(&cnt[dst[i]], 1);
}

// scan stage 1 + dis = rsqrt(1+deg) fused
__global__ __launch_bounds__(256) void k_scan1(const int* __restrict__ cnt,
                                               int* __restrict__ row_ptr,
                                               int* __restrict__ bsum,
                                               float* __restrict__ dis, int n) {
    __shared__ int s[256];
    int i = blockIdx.x * 256 + threadIdx.x;
    int v = (i < n) ? cnt[i] : 0;
    if (i < n) dis[i] = rsqrtf(1.0f + (float)v);
    s[threadIdx.x] = v;
    __syncthreads();
    for (int o = 1; o < 256; o <<= 1) {
        int t = (threadIdx.x >= o) ? s[threadIdx.x - o] : 0;
        __syncthreads();
        s[threadIdx.x] += t;
        __syncthreads();
    }
    if (i < n) row_ptr[i] = s[threadIdx.x] - v;  // exclusive
    if (threadIdx.x == 255) bsum[blockIdx.x] = s[255];
}

__global__ __launch_bounds__(256) void k_scan2(int* __restrict__ bsum, int nb) {
    __shared__ int s[256];
    int v = (threadIdx.x < nb) ? bsum[threadIdx.x] : 0;
    s[threadIdx.x] = v;
    __syncthreads();
    for (int o = 1; o < 256; o <<= 1) {
        int t = (threadIdx.x >= o) ? s[threadIdx.x - o] : 0;
        __syncthreads();
        s[threadIdx.x] += t;
        __syncthreads();
    }
    if (threadIdx.x < nb) bsum[threadIdx.x] = s[threadIdx.x] - v;
}

__global__ void k_scan3(int* __restrict__ row_ptr, const int* __restrict__ bsum, int n) {
    int i = blockIdx.x * 256 + threadIdx.x;
    if (i < n) row_ptr[i] += bsum[blockIdx.x];
}

__global__ void k_place(const int* __restrict__ ei, const int* __restrict__ row_ptr,
                        int* __restrict__ fill, int* __restrict__ srcs, int e) {
    int i = blockIdx.x * blockDim.x + threadIdx.x;
    if (i < e) {
        int s_ = ei[i];
        int d_ = ei[e + i];
        int pos = row_ptr[d_] + atomicAdd(&fill[d_], 1);
        srcs[pos] = s_;
    }
}

// ========= GEMM: Y[r][c] = dis[r] * sum_k X[r][k]*W[k][c] =========
// 64x128 tile, BK=32, 256 threads, 4x8 micro-tile. Cols split tx*4 / tx*4+64
// so sB b128 reads are 2-way bank-aliased (free). 782 blocks -> ~3/CU resident.

__global__ __launch_bounds__(256) void k_gemm_scale(
    const float* __restrict__ X, const float* __restrict__ W,
    const float* __restrict__ dis, float* __restrict__ Y, int nrows) {
    __shared__ float sA[GBK][GBM + 4];  // [k][m], stride 68 (16B-aligned rows)
    __shared__ float sB[GBK][D];        // [k][n]
    int tid = threadIdx.x;
    int tx = tid & 15;   // cols tx*4..+3 and tx*4+64..+3
    int ty = tid >> 4;   // rows ty*4..+3
    int row0 = blockIdx.x * GBM;

    float acc[4][8] = {};

    for (int kc = 0; kc < D; kc += GBK) {
        __syncthreads();
        // stage A: 64 rows x 32 k, transposed. 512 float4 -> 2/thread
        #pragma unroll
        for (int jj = 0; jj < 2; ++jj) {
            int i = tid + jj * 256;
            int r = i >> 3;             // 0..63
            int kq = i & 7;             // float4 within k-window
            int gr = row0 + r;
            float4 v = make_float4(0.f, 0.f, 0.f, 0.f);
            if (gr < nrows) v = *(const float4*)(X + (size_t)gr * D + kc + kq * 4);
            sA[kq * 4 + 0][r] = v.x;
            sA[kq * 4 + 1][r] = v.y;
            sA[kq * 4 + 2][r] = v.z;
            sA[kq * 4 + 3][r] = v.w;
        }
        // stage B: 32 k x 128 cols = 1024 float4 -> 4/thread, coalesced
        #pragma unroll
        for (int jj = 0; jj < 4; ++jj) {
            int i = tid + jj * 256;
            int k = i >> 5;             // 0..31
            int nq = i & 31;            // float4 col
            *(float4*)(&sB[k][nq * 4]) = *(const float4*)(W + (size_t)(kc + k) * D + nq * 4);
        }
        __syncthreads();
        #pragma unroll
        for (int k = 0; k < GBK; ++k) {
            float a[4], b[8];
            *(float4*)&a[0] = *(float4*)&sA[k][ty * 4];
            *(float4*)&b[0] = *(float4*)&sB[k][tx * 4];
            *(float4*)&b[4] = *(float4*)&sB[k][tx * 4 + 64];
            #pragma unroll
            for (int i = 0; i < 4; ++i)
                #pragma unroll
                for (int j2 = 0; j2 < 8; ++j2)
                    acc[i][j2] += a[i] * b[j2];
        }
    }
    #pragma unroll
    for (int i = 0; i < 4; ++i) {
        int gr = row0 + ty * 4 + i;
        if (gr < nrows) {
            float dv = dis[gr];
            float4 o0, o1;
            o0.x = acc[i][0] * dv; o0.y = acc[i][1] * dv;
            o0.z = acc[i][2] * dv; o0.w = acc[i][3] * dv;
            o1.x = acc[i][4] * dv; o1.y = acc[i][5] * dv;
            o1.z = acc[i][6] * dv; o1.w = acc[i][7] * dv;
            *(float4*)(Y + (size_t)gr * D + tx * 4) = o0;
            *(float4*)(Y + (size_t)gr * D + tx * 4 + 64) = o1;
        }
    }
}

// ================= fused aggregate + norm + bias (+relu) =================
// 32 lanes per node, float4 per lane. 4-deep gather pipeline for MLP.

template <bool RELU>
__global__ __launch_bounds__(256) void k_aggregate(
    const float* __restrict__ g, const int* __restrict__ row_ptr,
    const int* __restrict__ cnt, const int* __restrict__ srcs,
    const float* __restrict__ dis, const float* __restrict__ b,
    float* __restrict__ out, int n) {
    long tid = (long)blockIdx.x * blockDim.x + threadIdx.x;
    int lane = (int)(tid & 31);
    int v = (int)(tid >> 5);
    if (v >= n) return;
    int beg = row_ptr[v];
    int c = cnt[v];
    const float4* g4 = (const float4*)g;
    float4 s0 = g4[(size_t)v * 32 + lane];  // self-loop term
    float4 a0 = make_float4(0.f, 0.f, 0.f, 0.f);
    float4 a1 = a0, a2 = a0, a3 = a0;
    int j = 0;
    for (; j + 4 <= c; j += 4) {
        int u0 = srcs[beg + j + 0];
        int u1 = srcs[beg + j + 1];
        int u2 = srcs[beg + j + 2];
        int u3 = srcs[beg + j + 3];
        float4 t0 = g4[(size_t)u0 * 32 + lane];
        float4 t1 = g4[(size_t)u1 * 32 + lane];
        float4 t2 = g4[(size_t)u2 * 32 + lane];
        float4 t3 = g4[(size_t)u3 * 32 + lane];
        a0.x += t0.x; a0.y += t0.y; a0.z += t0.z; a0.w += t0.w;
        a1.x += t1.x; a1.y += t1.y; a1.z += t1.z; a1.w += t1.w;
        a2.x += t2.x; a2.y += t2.y; a2.z += t2.z; a2.w += t2.w;
        a3.x += t3.x; a3.y += t3.y; a3.z += t3.z; a3.w += t3.w;
    }
    for (; j < c; ++j) {
        int u = srcs[beg + j];
        float4 t = g4[(size_t)u * 32 + lane];
        a0.x += t.x; a0.y += t.y; a0.z += t.z; a0.w += t.w;
    }
    float4 acc;
    acc.x = s0.x + (a0.x + a1.x) + (a2.x + a3.x);
    acc.y = s0.y + (a0.y + a1.y) + (a2.y + a3.y);
    acc.z = s0.z + (a0.z + a1.z) + (a2.z + a3.z);
    acc.w = s0.w + (a0.w + a1.w) + (a2.w + a3.w);
    float dv = dis[v];
    float4 bb = ((const float4*)b)[lane];
    acc.x = acc.x * dv + bb.x;
    acc.y = acc.y * dv + bb.y;
    acc.z = acc.z * dv + bb.z;
    acc.w = acc.w * dv + bb.w;
    if (RELU) {
        acc.x = fmaxf(acc.x, 0.f);
        acc.y = fmaxf(acc.y, 0.f);
        acc.z = fmaxf(acc.z, 0.f);
        acc.w = fmaxf(acc.w, 0.f);
    }
    ((float4*)out)[(size_t)v * 32 + lane] = acc;
}

// ================= launch =================

extern "C" void kernel_launch(void* const* d_in, const int* in_sizes, int n_in,
                              void* d_out, int out_size, void* d_ws, size_t ws_size,
                              hipStream_t stream) {
    const float* x  = (const float*)d_in[0];
    const int*   ei = (const int*)d_in[1];
    const float* W1 = (const float*)d_in[2];
    const float* b1 = (const float*)d_in[3];
    const float* W2 = (const float*)d_in[4];
    const float* b2 = (const float*)d_in[5];
    float* out = (float*)d_out;
    int n = in_sizes[0] / D;
    int e = in_sizes[1] / 2;

    char* p = (char*)d_ws;
    auto alloc = [&](size_t bytes) -> char* {
        char* r = p;
        p += (bytes + 255) & ~(size_t)255;
        return r;
    };
    int* cnt     = (int*)alloc((size_t)n * 4);
    int* fill    = (int*)alloc((size_t)n * 4);
    int* row_ptr = (int*)alloc((size_t)n * 4);
    int* bsum    = (int*)alloc(1024);
    float* dis   = (float*)alloc((size_t)n * 4);
    int* srcs    = (int*)alloc((size_t)e * 4);
    float* bufA  = (float*)alloc((size_t)n * D * 4);
    float* bufB  = (float*)alloc((size_t)n * D * 4);

    hipMemsetAsync(cnt, 0, (size_t)n * 4, stream);
    hipMemsetAsync(fill, 0, (size_t)n * 4, stream);

    int nb = (n + 255) / 256;
    k_count<<<(e + 255) / 256, 256, 0, stream>>>(ei + e, cnt, e);
    k_scan1<<<nb, 256, 0, stream>>>(cnt, row_ptr, bsum, dis, n);
    k_scan2<<<1, 256, 0, stream>>>(bsum, nb);
    k_scan3<<<nb, 256, 0, stream>>>(row_ptr, bsum, n);
    k_place<<<(e + 255) / 256, 256, 0, stream>>>(ei, row_ptr, fill, srcs, e);

    int gemm_blocks = (n + GBM - 1) / GBM;
    int agg_blocks = (int)(((long)n * 32 + 255) / 256);

    // layer 1
    k_gemm_scale<<<gemm_blocks, 256, 0, stream>>>(x, W1, dis, bufA, n);
    k_aggregate<true><<<agg_blocks, 256, 0, stream>>>(bufA, row_ptr, cnt, srcs, dis, b1, bufB, n);
    // layer 2
    k_gemm_scale<<<gemm_blocks, 256, 0, stream>>>(bufB, W2, dis, bufA, n);
    k_aggregate<false><<<agg_blocks, 256, 0, stream>>>(bufA, row_ptr, cnt, srcs, dis, b2, out, n);
}

// Round 7
// 339.570 us; speedup vs baseline: 9.2539x; 1.0107x over previous
//
#include <hip/hip_runtime.h>

#define D 128
#define GBM 64
#define GBK 32

typedef float f32x4 __attribute__((ext_vector_type(4)));

// ================= CSR build (counting sort by dst) =================

__global__ void k_count(const int* __restrict__ dst, int* __restrict__ cnt, int e) {
    int i = blockIdx.x * blockDim.x + threadIdx.x;
    if (i < e) atomicAdd(&cnt[dst[i]], 1);
}

// scan stage 1 (per-block exclusive scan) + dis = rsqrt(1+deg) fused
__global__ __launch_bounds__(256) void k_scan1(const int* __restrict__ cnt,
                                               int* __restrict__ row_ptr,
                                               int* __restrict__ bsum,
                                               float* __restrict__ dis, int n) {
    __shared__ int s[256];
    int i = blockIdx.x * 256 + threadIdx.x;
    int v = (i < n) ? cnt[i] : 0;
    if (i < n) dis[i] = rsqrtf(1.0f + (float)v);
    s[threadIdx.x] = v;
    __syncthreads();
    for (int o = 1; o < 256; o <<= 1) {
        int t = (threadIdx.x >= o) ? s[threadIdx.x - o] : 0;
        __syncthreads();
        s[threadIdx.x] += t;
        __syncthreads();
    }
    if (i < n) row_ptr[i] = s[threadIdx.x] - v;  // block-local exclusive
    if (threadIdx.x == 255) bsum[blockIdx.x] = s[255];
}

__global__ __launch_bounds__(256) void k_scan2(int* __restrict__ bsum, int nb) {
    __shared__ int s[256];
    int v = (threadIdx.x < nb) ? bsum[threadIdx.x] : 0;
    s[threadIdx.x] = v;
    __syncthreads();
    for (int o = 1; o < 256; o <<= 1) {
        int t = (threadIdx.x >= o) ? s[threadIdx.x - o] : 0;
        __syncthreads();
        s[threadIdx.x] += t;
        __syncthreads();
    }
    if (threadIdx.x < nb) bsum[threadIdx.x] = s[threadIdx.x] - v;
}

// place src ids into dst-sorted order; bsum add fused here (no scan3 pass)
__global__ void k_place(const int* __restrict__ ei, const int* __restrict__ row_ptr,
                        const int* __restrict__ bsum,
                        int* __restrict__ fill, int* __restrict__ srcs, int e) {
    int i = blockIdx.x * blockDim.x + threadIdx.x;
    if (i < e) {
        int s_ = ei[i];
        int d_ = ei[e + i];
        int pos = row_ptr[d_] + bsum[d_ >> 8] + atomicAdd(&fill[d_], 1);
        srcs[pos] = s_;
    }
}

// ========= GEMM: Y[r][c] = dis[r] * sum_k X[r][k]*W[k][c] =========
// 64x128 tile, BK=32, 256 threads, 4x8 micro-tile, register-prefetch
// double-buffering: next chunk's global loads issue right after the barrier
// and drain during the 2048-cycle FMA block (T14 issue-early/write-late).

__global__ __launch_bounds__(256, 4) void k_gemm_scale(
    const float* __restrict__ X, const float* __restrict__ W,
    const float* __restrict__ dis, float* __restrict__ Y, int nrows) {
    __shared__ float sA[GBK][GBM + 4];  // [k][m], stride 68
    __shared__ float sB[GBK][D];        // [k][n]
    int tid = threadIdx.x;
    int tx = tid & 15;   // cols tx*4..+3 and tx*4+64..+3 (2-way bank alias = free)
    int ty = tid >> 4;   // rows ty*4..+3
    int row0 = blockIdx.x * GBM;

    int ar  = tid >> 3;  // 0..31 (rows ar, ar+32)
    int akq = tid & 7;   // float4 index within 32-k window
    int bk  = tid >> 5;  // 0..7 (k rows bk, bk+8, bk+16, bk+24)
    int bnq = tid & 31;  // float4 col

    float4 ra0, ra1, rb0, rb1, rb2, rb3;
    int gr0 = row0 + ar, gr1 = row0 + ar + 32;

    // prologue: load chunk 0
    ra0 = make_float4(0.f, 0.f, 0.f, 0.f); ra1 = ra0;
    if (gr0 < nrows) ra0 = *(const float4*)(X + (size_t)gr0 * D + akq * 4);
    if (gr1 < nrows) ra1 = *(const float4*)(X + (size_t)gr1 * D + akq * 4);
    rb0 = *(const float4*)(W + (size_t)(bk     ) * D + bnq * 4);
    rb1 = *(const float4*)(W + (size_t)(bk +  8) * D + bnq * 4);
    rb2 = *(const float4*)(W + (size_t)(bk + 16) * D + bnq * 4);
    rb3 = *(const float4*)(W + (size_t)(bk + 24) * D + bnq * 4);

    float acc[4][8] = {};

    for (int kc = 0; kc < D; kc += GBK) {
        if (kc) __syncthreads();  // previous chunk's readers done
        sA[akq * 4 + 0][ar]      = ra0.x;
        sA[akq * 4 + 1][ar]      = ra0.y;
        sA[akq * 4 + 2][ar]      = ra0.z;
        sA[akq * 4 + 3][ar]      = ra0.w;
        sA[akq * 4 + 0][ar + 32] = ra1.x;
        sA[akq * 4 + 1][ar + 32] = ra1.y;
        sA[akq * 4 + 2][ar + 32] = ra1.z;
        sA[akq * 4 + 3][ar + 32] = ra1.w;
        *(float4*)&sB[bk     ][bnq * 4] = rb0;
        *(float4*)&sB[bk +  8][bnq * 4] = rb1;
        *(float4*)&sB[bk + 16][bnq * 4] = rb2;
        *(float4*)&sB[bk + 24][bnq * 4] = rb3;
        __syncthreads();
        int kn = kc + GBK;
        if (kn < D) {  // issue next chunk's loads; drain under compute
            ra0 = make_float4(0.f, 0.f, 0.f, 0.f); ra1 = ra0;
            if (gr0 < nrows) ra0 = *(const float4*)(X + (size_t)gr0 * D + kn + akq * 4);
            if (gr1 < nrows) ra1 = *(const float4*)(X + (size_t)gr1 * D + kn + akq * 4);
            rb0 = *(const float4*)(W + (size_t)(kn + bk     ) * D + bnq * 4);
            rb1 = *(const float4*)(W + (size_t)(kn + bk +  8) * D + bnq * 4);
            rb2 = *(const float4*)(W + (size_t)(kn + bk + 16) * D + bnq * 4);
            rb3 = *(const float4*)(W + (size_t)(kn + bk + 24) * D + bnq * 4);
        }
        #pragma unroll
        for (int k = 0; k < GBK; ++k) {
            float a[4], b[8];
            *(float4*)&a[0] = *(float4*)&sA[k][ty * 4];
            *(float4*)&b[0] = *(float4*)&sB[k][tx * 4];
            *(float4*)&b[4] = *(float4*)&sB[k][tx * 4 + 64];
            #pragma unroll
            for (int i = 0; i < 4; ++i)
                #pragma unroll
                for (int j2 = 0; j2 < 8; ++j2)
                    acc[i][j2] += a[i] * b[j2];
        }
    }
    #pragma unroll
    for (int i = 0; i < 4; ++i) {
        int gr = row0 + ty * 4 + i;
        if (gr < nrows) {
            float dv = dis[gr];
            float4 o0, o1;
            o0.x = acc[i][0] * dv; o0.y = acc[i][1] * dv;
            o0.z = acc[i][2] * dv; o0.w = acc[i][3] * dv;
            o1.x = acc[i][4] * dv; o1.y = acc[i][5] * dv;
            o1.z = acc[i][6] * dv; o1.w = acc[i][7] * dv;
            *(float4*)(Y + (size_t)gr * D + tx * 4) = o0;
            *(float4*)(Y + (size_t)gr * D + tx * 4 + 64) = o1;
        }
    }
}

// ================= fused aggregate + norm + bias (+relu) =================
// 32 lanes per node, float4 per lane; 8-deep gather pipeline; nt output store.

template <bool RELU>
__global__ __launch_bounds__(256) void k_aggregate(
    const float* __restrict__ g, const int* __restrict__ row_ptr,
    const int* __restrict__ bsum, const int* __restrict__ cnt,
    const int* __restrict__ srcs, const float* __restrict__ dis,
    const float* __restrict__ b, float* __restrict__ out, int n) {
    long tid = (long)blockIdx.x * blockDim.x + threadIdx.x;
    int lane = (int)(tid & 31);
    int v = (int)(tid >> 5);
    if (v >= n) return;
    int beg = row_ptr[v] + bsum[v >> 8];
    int c = cnt[v];
    const float4* g4 = (const float4*)g;
    float4 s0 = g4[(size_t)v * 32 + lane];  // self-loop term
    float4 a0 = make_float4(0.f, 0.f, 0.f, 0.f);
    float4 a1 = a0;
    int j = 0;
    for (; j + 8 <= c; j += 8) {
        int u0 = srcs[beg + j + 0];
        int u1 = srcs[beg + j + 1];
        int u2 = srcs[beg + j + 2];
        int u3 = srcs[beg + j + 3];
        int u4 = srcs[beg + j + 4];
        int u5 = srcs[beg + j + 5];
        int u6 = srcs[beg + j + 6];
        int u7 = srcs[beg + j + 7];
        float4 t0 = g4[(size_t)u0 * 32 + lane];
        float4 t1 = g4[(size_t)u1 * 32 + lane];
        float4 t2 = g4[(size_t)u2 * 32 + lane];
        float4 t3 = g4[(size_t)u3 * 32 + lane];
        float4 t4 = g4[(size_t)u4 * 32 + lane];
        float4 t5 = g4[(size_t)u5 * 32 + lane];
        float4 t6 = g4[(size_t)u6 * 32 + lane];
        float4 t7 = g4[(size_t)u7 * 32 + lane];
        a0.x += t0.x; a0.y += t0.y; a0.z += t0.z; a0.w += t0.w;
        a1.x += t1.x; a1.y += t1.y; a1.z += t1.z; a1.w += t1.w;
        a0.x += t2.x; a0.y += t2.y; a0.z += t2.z; a0.w += t2.w;
        a1.x += t3.x; a1.y += t3.y; a1.z += t3.z; a1.w += t3.w;
        a0.x += t4.x; a0.y += t4.y; a0.z += t4.z; a0.w += t4.w;
        a1.x += t5.x; a1.y += t5.y; a1.z += t5.z; a1.w += t5.w;
        a0.x += t6.x; a0.y += t6.y; a0.z += t6.z; a0.w += t6.w;
        a1.x += t7.x; a1.y += t7.y; a1.z += t7.z; a1.w += t7.w;
    }
    for (; j + 2 <= c; j += 2) {
        int u0 = srcs[beg + j + 0];
        int u1 = srcs[beg + j + 1];
        float4 t0 = g4[(size_t)u0 * 32 + lane];
        float4 t1 = g4[(size_t)u1 * 32 + lane];
        a0.x += t0.x; a0.y += t0.y; a0.z += t0.z; a0.w += t0.w;
        a1.x += t1.x; a1.y += t1.y; a1.z += t1.z; a1.w += t1.w;
    }
    if (j < c) {
        int u0 = srcs[beg + j];
        float4 t0 = g4[(size_t)u0 * 32 + lane];
        a0.x += t0.x; a0.y += t0.y; a0.z += t0.z; a0.w += t0.w;
    }
    float4 acc;
    acc.x = s0.x + a0.x + a1.x;
    acc.y = s0.y + a0.y + a1.y;
    acc.z = s0.z + a0.z + a1.z;
    acc.w = s0.w + a0.w + a1.w;
    float dv = dis[v];
    float4 bb = ((const float4*)b)[lane];
    acc.x = acc.x * dv + bb.x;
    acc.y = acc.y * dv + bb.y;
    acc.z = acc.z * dv + bb.z;
    acc.w = acc.w * dv + bb.w;
    if (RELU) {
        acc.x = fmaxf(acc.x, 0.f);
        acc.y = fmaxf(acc.y, 0.f);
        acc.z = fmaxf(acc.z, 0.f);
        acc.w = fmaxf(acc.w, 0.f);
    }
    // nt store via native clang vector (builtin rejects HIP_vector_type)
    f32x4 nv = {acc.x, acc.y, acc.z, acc.w};
    __builtin_nontemporal_store(nv, (f32x4*)(out + (size_t)v * D + lane * 4));
}

// ================= launch =================

extern "C" void kernel_launch(void* const* d_in, const int* in_sizes, int n_in,
                              void* d_out, int out_size, void* d_ws, size_t ws_size,
                              hipStream_t stream) {
    const float* x  = (const float*)d_in[0];
    const int*   ei = (const int*)d_in[1];
    const float* W1 = (const float*)d_in[2];
    const float* b1 = (const float*)d_in[3];
    const float* W2 = (const float*)d_in[4];
    const float* b2 = (const float*)d_in[5];
    float* out = (float*)d_out;
    int n = in_sizes[0] / D;
    int e = in_sizes[1] / 2;

    char* p = (char*)d_ws;
    auto alloc = [&](size_t bytes) -> char* {
        char* r = p;
        p += (bytes + 255) & ~(size_t)255;
        return r;
    };
    size_t na = (((size_t)n * 4) + 255) & ~(size_t)255;
    int* cnt     = (int*)alloc((size_t)n * 4);
    int* fill    = (int*)alloc((size_t)n * 4);   // contiguous with cnt
    int* row_ptr = (int*)alloc((size_t)n * 4);
    int* bsum    = (int*)alloc(1024);
    float* dis   = (float*)alloc((size_t)n * 4);
    int* srcs    = (int*)alloc((size_t)e * 4);
    float* bufA  = (float*)alloc((size_t)n * D * 4);
    float* bufB  = (float*)alloc((size_t)n * D * 4);

    (void)hipMemsetAsync(cnt, 0, na * 2, stream);  // zeroes cnt + fill in one call

    int nb = (n + 255) / 256;
    k_count<<<(e + 255) / 256, 256, 0, stream>>>(ei + e, cnt, e);
    k_scan1<<<nb, 256, 0, stream>>>(cnt, row_ptr, bsum, dis, n);
    k_scan2<<<1, 256, 0, stream>>>(bsum, nb);
    k_place<<<(e + 255) / 256, 256, 0, stream>>>(ei, row_ptr, bsum, fill, srcs, e);

    int gemm_blocks = (n + GBM - 1) / GBM;
    int agg_blocks = (int)(((long)n * 32 + 255) / 256);

    // layer 1
    k_gemm_scale<<<gemm_blocks, 256, 0, stream>>>(x, W1, dis, bufA, n);
    k_aggregate<true><<<agg_blocks, 256, 0, stream>>>(bufA, row_ptr, bsum, cnt, srcs, dis, b1, bufB, n);
    // layer 2
    k_gemm_scale<<<gemm_blocks, 256, 0, stream>>>(bufB, W2, dis, bufA, n);
    k_aggregate<false><<<agg_blocks, 256, 0, stream>>>(bufA, row_ptr, bsum, cnt, srcs, dis, b2, out, n);
}